// Round 2
// baseline (187.798 us; speedup 1.0000x reference)
//
#include <hip/hip_runtime.h>
#include <hip/hip_bf16.h>

#define Bn 4096
#define Dk 1024
#define EPSF 1e-7f

typedef int i32x4 __attribute__((ext_vector_type(4)));
typedef int i32x8 __attribute__((ext_vector_type(8)));
typedef float f32x4 __attribute__((ext_vector_type(4)));

__device__ __forceinline__ void async_copy16(const void* g, void* l) {
    __builtin_amdgcn_global_load_lds((__attribute__((address_space(1))) void*)(uintptr_t)g,
                                     (__attribute__((address_space(3))) void*)l, 16, 0, 0);
}

// -------- Kernel 1: L2-normalize rows -> fp8 e4m3 (x8 prescale); exact f32 diag; zero sums ----
// prescale by 8 puts element RMS at ~0.25 (good e4m3 mantissa use); compensated by
// E8M0 block scale 2^-3 on BOTH gemm operands (2^-6 total on products).
__global__ __launch_bounds__(256)
void nrm_kernel(const float4* __restrict__ left, const float4* __restrict__ right,
                unsigned* __restrict__ lnb8, unsigned* __restrict__ rnb8,
                float* __restrict__ diag, float* __restrict__ rowsum,
                float* __restrict__ colsum)
{
    const int row = blockIdx.x;
    const int t = threadIdx.x;
    const int idx = row * (Dk / 4) + t;
    const float4 l = left[idx];
    const float4 r = right[idx];
    float sl = l.x * l.x + l.y * l.y + l.z * l.z + l.w * l.w;
    float sr = r.x * r.x + r.y * r.y + r.z * r.z + r.w * r.w;
    float slr = l.x * r.x + l.y * r.y + l.z * r.z + l.w * r.w;
    #pragma unroll
    for (int off = 1; off < 64; off <<= 1) {
        sl += __shfl_xor(sl, off);
        sr += __shfl_xor(sr, off);
        slr += __shfl_xor(slr, off);
    }
    __shared__ float red[3][4];
    const int wave = t >> 6, lane = t & 63;
    if (lane == 0) { red[0][wave] = sl; red[1][wave] = sr; red[2][wave] = slr; }
    __syncthreads();
    sl = red[0][0] + red[0][1] + red[0][2] + red[0][3];
    sr = red[1][0] + red[1][1] + red[1][2] + red[1][3];
    const float invl = 1.0f / sqrtf(fmaxf(sl, EPSF));
    const float invr = 1.0f / sqrtf(fmaxf(sr, EPSF));
    const float sL = 8.0f * invl;
    const float sR = 8.0f * invr;
    int pkL = __builtin_amdgcn_cvt_pk_fp8_f32(l.x * sL, l.y * sL, 0, false);
    pkL = __builtin_amdgcn_cvt_pk_fp8_f32(l.z * sL, l.w * sL, pkL, true);
    int pkR = __builtin_amdgcn_cvt_pk_fp8_f32(r.x * sR, r.y * sR, 0, false);
    pkR = __builtin_amdgcn_cvt_pk_fp8_f32(r.z * sR, r.w * sR, pkR, true);
    lnb8[idx] = (unsigned)pkL;
    rnb8[idx] = (unsigned)pkR;
    if (t == 0) {
        const float d = red[2][0] + red[2][1] + red[2][2] + red[2][3];
        diag[row] = d * invl * invr;
        rowsum[row] = 0.f;
        colsum[row] = 0.f;
    }
}

// -------- Kernel 2: S = ln . rn^T via MX-fp8 MFMA (16x16x128, K-block scale 2^-3 each op) ----
// 128x128 tile, BK=128 fp8 bytes, 4 waves 2x2, each wave 4x4 of 16x16 frags.
// LDS XOR-swizzle: LDS[row][chunk16 p] holds global chunk16 p^(row&7). Staging keeps
// global_load_lds's contiguous-LDS constraint (permute applied on the GLOBAL address);
// ds_read phase then hits 8 distinct 4-bank groups per 16-lane phase -> conflict-free.
__global__ __launch_bounds__(256, 2)
void gemm_sm_kernel(const unsigned char* __restrict__ lnb8,
                    const unsigned char* __restrict__ rnb8,
                    const float* __restrict__ temp,
                    float* __restrict__ rowsum, float* __restrict__ colsum)
{
    __shared__ __align__(16) unsigned char As[128 * 128];
    __shared__ __align__(16) unsigned char Bs[128 * 128];

    const int tid = threadIdx.x;
    const int wave = tid >> 6;
    const int lane = tid & 63;
    const int bm0 = blockIdx.y * 128;
    const int bn0 = blockIdx.x * 128;

    // ---- staging addressing: wave w stages tile rows [w*32, w*32+32), 4 chunks of 8 rows
    const int lr = lane >> 3;                 // row within 8-row chunk
    const int lc = lane & 7;                  // chunk16 slot within row
    const int gcol = (lc ^ lr) * 16;          // swizzled global byte offset within row slice
    const unsigned char* gA[4];
    const unsigned char* gB[4];
    unsigned char* lA[4];
    unsigned char* lB[4];
    #pragma unroll
    for (int c8 = 0; c8 < 4; ++c8) {
        const int rloc = wave * 32 + c8 * 8;              // LDS row base (wave-uniform)
        gA[c8] = lnb8 + (size_t)(bm0 + rloc + lr) * Dk + gcol;
        gB[c8] = rnb8 + (size_t)(bn0 + rloc + lr) * Dk + gcol;
        lA[c8] = As + rloc * 128;
        lB[c8] = Bs + rloc * 128;
    }

    const int wm = (wave & 1) * 64;
    const int wn = (wave >> 1) * 64;
    const int quad = lane >> 4;
    const int r16 = lane & 15;
    const int key = r16 & 7;
    const int c0 = ((quad * 2) ^ key) * 16;       // physical byte off of logical chunk quad*2
    const int c1 = ((quad * 2 + 1) ^ key) * 16;   // ... of logical chunk quad*2+1

    int arow[4], brow[4];
    #pragma unroll
    for (int i = 0; i < 4; ++i) {
        arow[i] = (wm + i * 16 + r16) * 128;
        brow[i] = (wn + i * 16 + r16) * 128;
    }

    f32x4 acc[4][4];
    #pragma unroll
    for (int i = 0; i < 4; ++i)
        #pragma unroll
        for (int j = 0; j < 4; ++j)
            acc[i][j] = (f32x4){0.f, 0.f, 0.f, 0.f};

    for (int k0 = 0; k0 < Dk; k0 += 128) {
        #pragma unroll
        for (int c8 = 0; c8 < 4; ++c8) {
            async_copy16(gA[c8] + k0, lA[c8]);
            async_copy16(gB[c8] + k0, lB[c8]);
        }
        __syncthreads();
        i32x8 af[4], bfv[4];
        #pragma unroll
        for (int i = 0; i < 4; ++i) {
            const i32x4 lo = *(const i32x4*)(As + arow[i] + c0);
            const i32x4 hi = *(const i32x4*)(As + arow[i] + c1);
            af[i] = __builtin_shufflevector(lo, hi, 0, 1, 2, 3, 4, 5, 6, 7);
        }
        #pragma unroll
        for (int i = 0; i < 4; ++i) {
            const i32x4 lo = *(const i32x4*)(Bs + brow[i] + c0);
            const i32x4 hi = *(const i32x4*)(Bs + brow[i] + c1);
            bfv[i] = __builtin_shufflevector(lo, hi, 0, 1, 2, 3, 4, 5, 6, 7);
        }
        #pragma unroll
        for (int mi = 0; mi < 4; ++mi)
            #pragma unroll
            for (int ni = 0; ni < 4; ++ni)
                acc[mi][ni] = __builtin_amdgcn_mfma_scale_f32_16x16x128_f8f6f4(
                    af[mi], bfv[ni], acc[mi][ni], 0, 0,   // cbsz=fp8 e4m3, blgp=fp8 e4m3
                    0, 124,                                // A scale: 2^(124-127)=2^-3
                    0, 124);                               // B scale: 2^-3
        __syncthreads();
    }

    // epilogue: p = exp(scale*s - scale)  (|s|<=1 so scale is a valid max bound)
    const float scale = __expf(temp[0]);
    #pragma unroll
    for (int mi = 0; mi < 4; ++mi)
        #pragma unroll
        for (int ni = 0; ni < 4; ++ni)
            #pragma unroll
            for (int r = 0; r < 4; ++r)
                acc[mi][ni][r] = __expf(scale * acc[mi][ni][r] - scale);

    // C/D layout: col = lane&15, row = quad*4 + reg
    #pragma unroll
    for (int mi = 0; mi < 4; ++mi) {
        #pragma unroll
        for (int r = 0; r < 4; ++r) {
            float v = acc[mi][0][r] + acc[mi][1][r] + acc[mi][2][r] + acc[mi][3][r];
            v += __shfl_xor(v, 1);
            v += __shfl_xor(v, 2);
            v += __shfl_xor(v, 4);
            v += __shfl_xor(v, 8);
            if (r16 == 0)
                atomicAdd(&rowsum[bm0 + wm + mi * 16 + quad * 4 + r], v);
        }
    }
    #pragma unroll
    for (int ni = 0; ni < 4; ++ni) {
        float v = 0.f;
        #pragma unroll
        for (int mi = 0; mi < 4; ++mi)
            #pragma unroll
            for (int r = 0; r < 4; ++r)
                v += acc[mi][ni][r];
        v += __shfl_xor(v, 16);
        v += __shfl_xor(v, 32);
        if (quad == 0)
            atomicAdd(&colsum[bn0 + wn + ni * 16 + r16], v);
    }
}

// -------- Kernel 3: final scalar loss --------
__global__ __launch_bounds__(256)
void loss_kernel(const float* __restrict__ diag, const float* __restrict__ rowsum,
                 const float* __restrict__ colsum, const float* __restrict__ temp,
                 float* __restrict__ out)
{
    const int t = threadIdx.x;
    const float scale = __expf(temp[0]);
    float dL = 0.f, dR = 0.f;
    for (int i = t; i < Bn; i += 256) {
        const float e = __expf(scale * (diag[i] - 1.0f));
        dL += e * __builtin_amdgcn_rcpf(rowsum[i]);
        dR += e * __builtin_amdgcn_rcpf(colsum[i]);
    }
    #pragma unroll
    for (int off = 1; off < 64; off <<= 1) {
        dL += __shfl_xor(dL, off);
        dR += __shfl_xor(dR, off);
    }
    __shared__ float rd[2][4];
    const int wave = t >> 6, lane = t & 63;
    if (lane == 0) { rd[0][wave] = dL; rd[1][wave] = dR; }
    __syncthreads();
    if (t == 0) {
        dL = rd[0][0] + rd[0][1] + rd[0][2] + rd[0][3];
        dR = rd[1][0] + rd[1][1] + rd[1][2] + rd[1][3];
        const float logeps = logf(EPSF);
        const float log1m = logf(1.0f - EPSF);
        const float lossL = -(dL * log1m + ((float)Bn - dL) * logeps);
        const float lossR = -(dR * log1m + ((float)Bn - dR) * logeps);
        out[0] = (lossL + lossR) * 0.5f / (float)Bn;
    }
}

extern "C" void kernel_launch(void* const* d_in, const int* in_sizes, int n_in,
                              void* d_out, int out_size, void* d_ws, size_t ws_size,
                              hipStream_t stream) {
    (void)in_sizes; (void)n_in; (void)out_size; (void)ws_size;
    const float* left = (const float*)d_in[0];
    const float* right = (const float*)d_in[1];
    const float* temp = (const float*)d_in[2];

    char* ws = (char*)d_ws;
    unsigned char* lnb8 = (unsigned char*)ws;                       // 4 MiB
    unsigned char* rnb8 = (unsigned char*)(ws + (size_t)Bn * Dk);   // 4 MiB
    float* diag = (float*)(ws + 2 * (size_t)Bn * Dk);
    float* rowsum = diag + Bn;
    float* colsum = rowsum + Bn;

    nrm_kernel<<<Bn, 256, 0, stream>>>((const float4*)left, (const float4*)right,
                                       (unsigned*)lnb8, (unsigned*)rnb8, diag, rowsum, colsum);
    dim3 g2(Bn / 128, Bn / 128);
    gemm_sm_kernel<<<g2, 256, 0, stream>>>(lnb8, rnb8, temp, rowsum, colsum);
    loss_kernel<<<1, 256, 0, stream>>>(diag, rowsum, colsum, temp, (float*)d_out);
}

// Round 3
// 174.381 us; speedup vs baseline: 1.0769x; 1.0769x over previous
//
#include <hip/hip_runtime.h>
#include <hip/hip_bf16.h>

#define Bn 4096
#define Dk 1024
#define EPSF 1e-7f

typedef int i32x4 __attribute__((ext_vector_type(4)));
typedef int i32x8 __attribute__((ext_vector_type(8)));
typedef float f32x16 __attribute__((ext_vector_type(16)));

__device__ __forceinline__ void async_copy16(const void* g, void* l) {
    __builtin_amdgcn_global_load_lds((__attribute__((address_space(1))) void*)(uintptr_t)g,
                                     (__attribute__((address_space(3))) void*)l, 16, 0, 0);
}

// -------- Kernel 1: L2-normalize rows -> fp8 e4m3 (x8 prescale); exact f32 diag; zero sums ----
__global__ __launch_bounds__(256)
void nrm_kernel(const float4* __restrict__ left, const float4* __restrict__ right,
                unsigned* __restrict__ lnb8, unsigned* __restrict__ rnb8,
                float* __restrict__ diag, float* __restrict__ rowsum,
                float* __restrict__ colsum)
{
    const int row = blockIdx.x;
    const int t = threadIdx.x;
    const int idx = row * (Dk / 4) + t;
    const float4 l = left[idx];
    const float4 r = right[idx];
    float sl = l.x * l.x + l.y * l.y + l.z * l.z + l.w * l.w;
    float sr = r.x * r.x + r.y * r.y + r.z * r.z + r.w * r.w;
    float slr = l.x * r.x + l.y * r.y + l.z * r.z + l.w * r.w;
    #pragma unroll
    for (int off = 1; off < 64; off <<= 1) {
        sl += __shfl_xor(sl, off);
        sr += __shfl_xor(sr, off);
        slr += __shfl_xor(slr, off);
    }
    __shared__ float red[3][4];
    const int wave = t >> 6, lane = t & 63;
    if (lane == 0) { red[0][wave] = sl; red[1][wave] = sr; red[2][wave] = slr; }
    __syncthreads();
    sl = red[0][0] + red[0][1] + red[0][2] + red[0][3];
    sr = red[1][0] + red[1][1] + red[1][2] + red[1][3];
    const float invl = 1.0f / sqrtf(fmaxf(sl, EPSF));
    const float invr = 1.0f / sqrtf(fmaxf(sr, EPSF));
    const float sL = 8.0f * invl;
    const float sR = 8.0f * invr;
    int pkL = __builtin_amdgcn_cvt_pk_fp8_f32(l.x * sL, l.y * sL, 0, false);
    pkL = __builtin_amdgcn_cvt_pk_fp8_f32(l.z * sL, l.w * sL, pkL, true);
    int pkR = __builtin_amdgcn_cvt_pk_fp8_f32(r.x * sR, r.y * sR, 0, false);
    pkR = __builtin_amdgcn_cvt_pk_fp8_f32(r.z * sR, r.w * sR, pkR, true);
    lnb8[idx] = (unsigned)pkL;
    rnb8[idx] = (unsigned)pkR;
    if (t == 0) {
        const float d = red[2][0] + red[2][1] + red[2][2] + red[2][3];
        diag[row] = d * invl * invr;
        rowsum[row] = 0.f;
        colsum[row] = 0.f;
    }
}

// -------- Kernel 2: S = ln . rn^T via MX-fp8 mfma_scale_f32_32x32x64 (scales 2^-3 each) ----
// 128x128 block tile, BK=128 bytes, 4 waves 2x2, each wave 64x64 = 2x2 frags of 32x32.
// XOR-swizzled LDS (chunk16 p of row r stored at p^(r&7)): staging stays contiguous for
// global_load_lds; ds_read_b128 phases hit all 32 banks at 2-way (free).
// Register budget: af[2]+bfv[2]=32 VGPR live (vs 64 in the spilling 16x16x128 version),
// acc 2x2x16 -> AGPR-eligible. No spill expected.
__global__ __launch_bounds__(256, 2)
void gemm_sm_kernel(const unsigned char* __restrict__ lnb8,
                    const unsigned char* __restrict__ rnb8,
                    const float* __restrict__ temp,
                    float* __restrict__ rowsum, float* __restrict__ colsum)
{
    __shared__ __align__(16) unsigned char As[128 * 128];
    __shared__ __align__(16) unsigned char Bs[128 * 128];

    const int tid = threadIdx.x;
    const int wave = tid >> 6;
    const int lane = tid & 63;
    const int bm0 = blockIdx.y * 128;
    const int bn0 = blockIdx.x * 128;

    // ---- staging: wave w stages tile rows [w*32, w*32+32) of both As and Bs
    const int lr = lane >> 3;                 // row within 8-row chunk
    const int lc = lane & 7;                  // chunk16 slot within row
    const int gcol = (lc ^ lr) * 16;          // swizzled source byte offset within row
    const unsigned char* baseA = lnb8 + (size_t)bm0 * Dk;
    const unsigned char* baseB = rnb8 + (size_t)bn0 * Dk;
    int goff[4];
    unsigned char* lA[4];
    unsigned char* lB[4];
    #pragma unroll
    for (int c8 = 0; c8 < 4; ++c8) {
        const int rloc = wave * 32 + c8 * 8;
        goff[c8] = (rloc + lr) * Dk + gcol;
        lA[c8] = As + rloc * 128;             // wave-uniform LDS base
        lB[c8] = Bs + rloc * 128;
    }

    // ---- compute-side addressing: 32x32x64 A/B layout row = lane&31, k-half = lane>>5
    const int wm = (wave & 1) * 64;
    const int wn = (wave >> 1) * 64;
    const int c31 = lane & 31;
    const int hl = lane >> 5;
    const int key = c31 & 7;
    int coff0[2], coff1[2];                   // physical byte offs of this lane's 2 chunks, per k-step
    #pragma unroll
    for (int ks = 0; ks < 2; ++ks) {
        coff0[ks] = ((ks * 4 + hl * 2) ^ key) * 16;
        coff1[ks] = ((ks * 4 + hl * 2 + 1) ^ key) * 16;
    }
    int arow[2], brow[2];
    #pragma unroll
    for (int i = 0; i < 2; ++i) {
        arow[i] = (wm + i * 32 + c31) * 128;
        brow[i] = (wn + i * 32 + c31) * 128;
    }

    f32x16 acc[2][2];
    #pragma unroll
    for (int i = 0; i < 2; ++i)
        #pragma unroll
        for (int j = 0; j < 2; ++j)
            acc[i][j] = (f32x16)(0.f);

    for (int k0 = 0; k0 < Dk; k0 += 128) {
        #pragma unroll
        for (int c8 = 0; c8 < 4; ++c8) {
            async_copy16(baseA + goff[c8] + k0, lA[c8]);
            async_copy16(baseB + goff[c8] + k0, lB[c8]);
        }
        __syncthreads();
        #pragma unroll
        for (int ks = 0; ks < 2; ++ks) {
            i32x8 af[2], bfv[2];
            #pragma unroll
            for (int i = 0; i < 2; ++i) {
                const i32x4 lo = *(const i32x4*)(As + arow[i] + coff0[ks]);
                const i32x4 hi = *(const i32x4*)(As + arow[i] + coff1[ks]);
                af[i] = __builtin_shufflevector(lo, hi, 0, 1, 2, 3, 4, 5, 6, 7);
            }
            #pragma unroll
            for (int i = 0; i < 2; ++i) {
                const i32x4 lo = *(const i32x4*)(Bs + brow[i] + coff0[ks]);
                const i32x4 hi = *(const i32x4*)(Bs + brow[i] + coff1[ks]);
                bfv[i] = __builtin_shufflevector(lo, hi, 0, 1, 2, 3, 4, 5, 6, 7);
            }
            #pragma unroll
            for (int mi = 0; mi < 2; ++mi)
                #pragma unroll
                for (int ni = 0; ni < 2; ++ni)
                    acc[mi][ni] = __builtin_amdgcn_mfma_scale_f32_32x32x64_f8f6f4(
                        af[mi], bfv[ni], acc[mi][ni], 0, 0,  // fp8 e4m3 / fp8 e4m3
                        0, 124,                               // A scale 2^-3
                        0, 124);                              // B scale 2^-3
        }
        __syncthreads();
    }

    // epilogue: p = exp(scale*s - scale)  (|s|<=1 so scale is a valid max bound)
    const float scale = __expf(temp[0]);
    #pragma unroll
    for (int mi = 0; mi < 2; ++mi)
        #pragma unroll
        for (int ni = 0; ni < 2; ++ni)
            #pragma unroll
            for (int r = 0; r < 16; ++r)
                acc[mi][ni][r] = __expf(scale * acc[mi][ni][r] - scale);

    // C/D 32x32 layout: col = lane&31, row = (r&3) + 8*(r>>2) + 4*hl
    #pragma unroll
    for (int mi = 0; mi < 2; ++mi) {
        #pragma unroll
        for (int r = 0; r < 16; ++r) {
            float v = acc[mi][0][r] + acc[mi][1][r];
            v += __shfl_xor(v, 1);
            v += __shfl_xor(v, 2);
            v += __shfl_xor(v, 4);
            v += __shfl_xor(v, 8);
            v += __shfl_xor(v, 16);
            if (c31 == 0)
                atomicAdd(&rowsum[bm0 + wm + mi * 32 + (r & 3) + 8 * (r >> 2) + 4 * hl], v);
        }
    }
    #pragma unroll
    for (int ni = 0; ni < 2; ++ni) {
        float v = 0.f;
        #pragma unroll
        for (int mi = 0; mi < 2; ++mi)
            #pragma unroll
            for (int r = 0; r < 16; ++r)
                v += acc[mi][ni][r];
        v += __shfl_xor(v, 32);
        if (hl == 0)
            atomicAdd(&colsum[bn0 + wn + ni * 32 + c31], v);
    }
}

// -------- Kernel 3: final scalar loss --------
__global__ __launch_bounds__(256)
void loss_kernel(const float* __restrict__ diag, const float* __restrict__ rowsum,
                 const float* __restrict__ colsum, const float* __restrict__ temp,
                 float* __restrict__ out)
{
    const int t = threadIdx.x;
    const float scale = __expf(temp[0]);
    float dL = 0.f, dR = 0.f;
    for (int i = t; i < Bn; i += 256) {
        const float e = __expf(scale * (diag[i] - 1.0f));
        dL += e * __builtin_amdgcn_rcpf(rowsum[i]);
        dR += e * __builtin_amdgcn_rcpf(colsum[i]);
    }
    #pragma unroll
    for (int off = 1; off < 64; off <<= 1) {
        dL += __shfl_xor(dL, off);
        dR += __shfl_xor(dR, off);
    }
    __shared__ float rd[2][4];
    const int wave = t >> 6, lane = t & 63;
    if (lane == 0) { rd[0][wave] = dL; rd[1][wave] = dR; }
    __syncthreads();
    if (t == 0) {
        dL = rd[0][0] + rd[0][1] + rd[0][2] + rd[0][3];
        dR = rd[1][0] + rd[1][1] + rd[1][2] + rd[1][3];
        const float logeps = logf(EPSF);
        const float log1m = logf(1.0f - EPSF);
        const float lossL = -(dL * log1m + ((float)Bn - dL) * logeps);
        const float lossR = -(dR * log1m + ((float)Bn - dR) * logeps);
        out[0] = (lossL + lossR) * 0.5f / (float)Bn;
    }
}

extern "C" void kernel_launch(void* const* d_in, const int* in_sizes, int n_in,
                              void* d_out, int out_size, void* d_ws, size_t ws_size,
                              hipStream_t stream) {
    (void)in_sizes; (void)n_in; (void)out_size; (void)ws_size;
    const float* left = (const float*)d_in[0];
    const float* right = (const float*)d_in[1];
    const float* temp = (const float*)d_in[2];

    char* ws = (char*)d_ws;
    unsigned char* lnb8 = (unsigned char*)ws;                       // 4 MiB
    unsigned char* rnb8 = (unsigned char*)(ws + (size_t)Bn * Dk);   // 4 MiB
    float* diag = (float*)(ws + 2 * (size_t)Bn * Dk);
    float* rowsum = diag + Bn;
    float* colsum = rowsum + Bn;

    nrm_kernel<<<Bn, 256, 0, stream>>>((const float4*)left, (const float4*)right,
                                       (unsigned*)lnb8, (unsigned*)rnb8, diag, rowsum, colsum);
    dim3 g2(Bn / 128, Bn / 128);
    gemm_sm_kernel<<<g2, 256, 0, stream>>>(lnb8, rnb8, temp, rowsum, colsum);
    loss_kernel<<<1, 256, 0, stream>>>(diag, rowsum, colsum, temp, (float*)d_out);
}

// Round 4
// 128.126 us; speedup vs baseline: 1.4657x; 1.3610x over previous
//
#include <hip/hip_runtime.h>
#include <hip/hip_bf16.h>

#define Bn 4096
#define Dk 1024
#define EPSF 1e-7f

typedef float f32x4 __attribute__((ext_vector_type(4)));

__device__ __forceinline__ void async_copy16(const void* g, void* l) {
    __builtin_amdgcn_global_load_lds((__attribute__((address_space(1))) void*)(uintptr_t)g,
                                     (__attribute__((address_space(3))) void*)l, 16, 0, 0);
}

// -------- Kernel 1: L2-normalize rows -> fp8 e4m3 (x8 prescale); exact f32 diag; zero sums ----
// prescale by 8 puts element RMS at ~0.25 (good e4m3 mantissa use); compensated exactly by
// multiplying the f32 accumulator by 2^-6 in the gemm epilogue.
__global__ __launch_bounds__(256)
void nrm_kernel(const float4* __restrict__ left, const float4* __restrict__ right,
                unsigned* __restrict__ lnb8, unsigned* __restrict__ rnb8,
                float* __restrict__ diag, float* __restrict__ rowsum,
                float* __restrict__ colsum)
{
    const int row = blockIdx.x;
    const int t = threadIdx.x;
    const int idx = row * (Dk / 4) + t;
    const float4 l = left[idx];
    const float4 r = right[idx];
    float sl = l.x * l.x + l.y * l.y + l.z * l.z + l.w * l.w;
    float sr = r.x * r.x + r.y * r.y + r.z * r.z + r.w * r.w;
    float slr = l.x * r.x + l.y * r.y + l.z * r.z + l.w * r.w;
    #pragma unroll
    for (int off = 1; off < 64; off <<= 1) {
        sl += __shfl_xor(sl, off);
        sr += __shfl_xor(sr, off);
        slr += __shfl_xor(slr, off);
    }
    __shared__ float red[3][4];
    const int wave = t >> 6, lane = t & 63;
    if (lane == 0) { red[0][wave] = sl; red[1][wave] = sr; red[2][wave] = slr; }
    __syncthreads();
    sl = red[0][0] + red[0][1] + red[0][2] + red[0][3];
    sr = red[1][0] + red[1][1] + red[1][2] + red[1][3];
    const float invl = 1.0f / sqrtf(fmaxf(sl, EPSF));
    const float invr = 1.0f / sqrtf(fmaxf(sr, EPSF));
    const float sL = 8.0f * invl;
    const float sR = 8.0f * invr;
    int pkL = __builtin_amdgcn_cvt_pk_fp8_f32(l.x * sL, l.y * sL, 0, false);
    pkL = __builtin_amdgcn_cvt_pk_fp8_f32(l.z * sL, l.w * sL, pkL, true);
    int pkR = __builtin_amdgcn_cvt_pk_fp8_f32(r.x * sR, r.y * sR, 0, false);
    pkR = __builtin_amdgcn_cvt_pk_fp8_f32(r.z * sR, r.w * sR, pkR, true);
    lnb8[idx] = (unsigned)pkL;
    rnb8[idx] = (unsigned)pkR;
    if (t == 0) {
        const float d = red[2][0] + red[2][1] + red[2][2] + red[2][3];
        diag[row] = d * invl * invr;
        rowsum[row] = 0.f;
        colsum[row] = 0.f;
    }
}

// -------- Kernel 2: S = ln . rn^T via NON-scaled fp8 mfma_f32_16x16x32_fp8_fp8 ----
// 128x128 tile, BK=64 fp8 bytes (2 k-steps/iter, 16 iters), 4 waves 2x2, each wave
// 64x64 = 4x4 frags. LDS rows 64 B, XOR swizzle at 8-B chunks with EVEN key (row&6):
//  - staging: 16-B granules stay contiguous (logical chunk16 j -> physical j^((r>>1)&3)),
//    so global_load_lds's wave-uniform-base+lane*16 constraint holds;
//  - compute: each ds_read_b64 spreads 128 bank-requests at exactly 4/bank (inherent
//    minimum) -> conflict-free.
// Accumulator 4x4xf32x4 = 64 regs -> AGPRs (non-scaled MFMA keeps AGPR path; the
// mfma_scale variant pinned C/D to arch VGPRs and spilled ~200 MB -> abandoned).
__global__ __launch_bounds__(256, 2)
void gemm_sm_kernel(const unsigned char* __restrict__ lnb8,
                    const unsigned char* __restrict__ rnb8,
                    const float* __restrict__ temp,
                    float* __restrict__ rowsum, float* __restrict__ colsum)
{
    __shared__ __align__(16) unsigned char As[128 * 64];
    __shared__ __align__(16) unsigned char Bs[128 * 64];

    const int tid = threadIdx.x;
    const int wave = tid >> 6;
    const int lane = tid & 63;
    const int bm0 = blockIdx.y * 128;
    const int bn0 = blockIdx.x * 128;

    // ---- staging: wave w stages rows [32w, 32w+32), 2 insts of 16 rows per matrix
    const int srow = lane >> 2;          // row within 16-row inst group
    const int sj = lane & 3;             // chunk16 slot within 64-B row
    int grow[2], gcol[2];
    unsigned char* lA[2];
    unsigned char* lB[2];
    #pragma unroll
    for (int i = 0; i < 2; ++i) {
        const int rloc = wave * 32 + i * 16 + srow;       // tile-local row
        grow[i] = rloc;
        gcol[i] = 16 * (sj ^ ((rloc >> 1) & 3));          // even-key swizzle, 16-B granular
        lA[i] = As + (wave * 32 + i * 16) * 64;           // wave-uniform base (+lane*16 implicit)
        lB[i] = Bs + (wave * 32 + i * 16) * 64;
    }
    const unsigned char* baseA = lnb8 + (size_t)bm0 * Dk;
    const unsigned char* baseB = rnb8 + (size_t)bn0 * Dk;

    // ---- compute-side: 16x16x32 fp8, lane = (quad = k-group, r16 = row/col)
    const int wm = (wave & 1) * 64;
    const int wn = (wave >> 1) * 64;
    const int quad = lane >> 4;
    const int r16 = lane & 15;
    const int key = r16 & 6;             // even XOR key at chunk8 granularity
    int aoff[4], boff[4];                // ks=0 offsets; ks=1 adds the bit2 flip
    #pragma unroll
    for (int i = 0; i < 4; ++i) {
        aoff[i] = (wm + i * 16 + r16) * 64 + 8 * (quad ^ key);
        boff[i] = (wn + i * 16 + r16) * 64 + 8 * (quad ^ key);
    }
    const int ks1d = 8 * ((4 + quad) ^ key) - 8 * (quad ^ key);  // delta to ks=1 chunk

    f32x4 acc[4][4];
    #pragma unroll
    for (int i = 0; i < 4; ++i)
        #pragma unroll
        for (int j = 0; j < 4; ++j)
            acc[i][j] = (f32x4){0.f, 0.f, 0.f, 0.f};

    for (int k0 = 0; k0 < Dk; k0 += 64) {
        #pragma unroll
        for (int i = 0; i < 2; ++i) {
            async_copy16(baseA + (size_t)grow[i] * Dk + k0 + gcol[i], lA[i]);
            async_copy16(baseB + (size_t)grow[i] * Dk + k0 + gcol[i], lB[i]);
        }
        __syncthreads();
        #pragma unroll
        for (int ks = 0; ks < 2; ++ks) {
            const int d = ks ? ks1d : 0;
            long af[4], bf[4];
            #pragma unroll
            for (int i = 0; i < 4; ++i) af[i] = *(const long*)(As + aoff[i] + d);
            #pragma unroll
            for (int i = 0; i < 4; ++i) bf[i] = *(const long*)(Bs + boff[i] + d);
            #pragma unroll
            for (int mi = 0; mi < 4; ++mi)
                #pragma unroll
                for (int ni = 0; ni < 4; ++ni)
                    acc[mi][ni] = __builtin_amdgcn_mfma_f32_16x16x32_fp8_fp8(
                        af[mi], bf[ni], acc[mi][ni], 0, 0, 0);
        }
        __syncthreads();
    }

    // epilogue: undo the 8x8 prescale (2^-6, exact), then p = exp(scale*s - scale)
    const float scale = __expf(temp[0]);
    const float dq = 0.015625f * scale;  // 2^-6 * scale
    #pragma unroll
    for (int mi = 0; mi < 4; ++mi)
        #pragma unroll
        for (int ni = 0; ni < 4; ++ni)
            #pragma unroll
            for (int r = 0; r < 4; ++r)
                acc[mi][ni][r] = __expf(dq * acc[mi][ni][r] - scale);

    // C/D layout: col = lane&15, row = quad*4 + reg
    #pragma unroll
    for (int mi = 0; mi < 4; ++mi) {
        #pragma unroll
        for (int r = 0; r < 4; ++r) {
            float v = acc[mi][0][r] + acc[mi][1][r] + acc[mi][2][r] + acc[mi][3][r];
            v += __shfl_xor(v, 1);
            v += __shfl_xor(v, 2);
            v += __shfl_xor(v, 4);
            v += __shfl_xor(v, 8);
            if (r16 == 0)
                atomicAdd(&rowsum[bm0 + wm + mi * 16 + quad * 4 + r], v);
        }
    }
    #pragma unroll
    for (int ni = 0; ni < 4; ++ni) {
        float v = 0.f;
        #pragma unroll
        for (int mi = 0; mi < 4; ++mi)
            #pragma unroll
            for (int r = 0; r < 4; ++r)
                v += acc[mi][ni][r];
        v += __shfl_xor(v, 16);
        v += __shfl_xor(v, 32);
        if (quad == 0)
            atomicAdd(&colsum[bn0 + wn + ni * 16 + r16], v);
    }
}

// -------- Kernel 3: final scalar loss --------
__global__ __launch_bounds__(256)
void loss_kernel(const float* __restrict__ diag, const float* __restrict__ rowsum,
                 const float* __restrict__ colsum, const float* __restrict__ temp,
                 float* __restrict__ out)
{
    const int t = threadIdx.x;
    const float scale = __expf(temp[0]);
    float dL = 0.f, dR = 0.f;
    for (int i = t; i < Bn; i += 256) {
        const float e = __expf(scale * (diag[i] - 1.0f));
        dL += e * __builtin_amdgcn_rcpf(rowsum[i]);
        dR += e * __builtin_amdgcn_rcpf(colsum[i]);
    }
    #pragma unroll
    for (int off = 1; off < 64; off <<= 1) {
        dL += __shfl_xor(dL, off);
        dR += __shfl_xor(dR, off);
    }
    __shared__ float rd[2][4];
    const int wave = t >> 6, lane = t & 63;
    if (lane == 0) { rd[0][wave] = dL; rd[1][wave] = dR; }
    __syncthreads();
    if (t == 0) {
        dL = rd[0][0] + rd[0][1] + rd[0][2] + rd[0][3];
        dR = rd[1][0] + rd[1][1] + rd[1][2] + rd[1][3];
        const float logeps = logf(EPSF);
        const float log1m = logf(1.0f - EPSF);
        const float lossL = -(dL * log1m + ((float)Bn - dL) * logeps);
        const float lossR = -(dR * log1m + ((float)Bn - dR) * logeps);
        out[0] = (lossL + lossR) * 0.5f / (float)Bn;
    }
}

extern "C" void kernel_launch(void* const* d_in, const int* in_sizes, int n_in,
                              void* d_out, int out_size, void* d_ws, size_t ws_size,
                              hipStream_t stream) {
    (void)in_sizes; (void)n_in; (void)out_size; (void)ws_size;
    const float* left = (const float*)d_in[0];
    const float* right = (const float*)d_in[1];
    const float* temp = (const float*)d_in[2];

    char* ws = (char*)d_ws;
    unsigned char* lnb8 = (unsigned char*)ws;                       // 4 MiB
    unsigned char* rnb8 = (unsigned char*)(ws + (size_t)Bn * Dk);   // 4 MiB
    float* diag = (float*)(ws + 2 * (size_t)Bn * Dk);
    float* rowsum = diag + Bn;
    float* colsum = rowsum + Bn;

    nrm_kernel<<<Bn, 256, 0, stream>>>((const float4*)left, (const float4*)right,
                                       (unsigned*)lnb8, (unsigned*)rnb8, diag, rowsum, colsum);
    dim3 g2(Bn / 128, Bn / 128);
    gemm_sm_kernel<<<g2, 256, 0, stream>>>(lnb8, rnb8, temp, rowsum, colsum);
    loss_kernel<<<1, 256, 0, stream>>>(diag, rowsum, colsum, temp, (float*)d_out);
}